// Round 8
// baseline (239.509 us; speedup 1.0000x reference)
//
#include <hip/hip_runtime.h>

#define DECAY 0.25f

typedef float fx4 __attribute__((ext_vector_type(4)));

__device__ __forceinline__ fx4 step4(fx4 mem, fx4 spk, fx4 xi, fx4* s_out)
{
    fx4 m = (mem - spk * 0.5f) * DECAY + xi;
    fx4 s;
    s.x = rintf(fminf(fmaxf(m.x, 0.f), 1.f));
    s.y = rintf(fminf(fmaxf(m.y, 0.f), 1.f));
    s.z = rintf(fminf(fmaxf(m.z, 0.f), 1.f));
    s.w = rintf(fminf(fmaxf(m.w, 0.f), 1.f));
    *s_out = s;
    return m;
}

// 2 blocks/CU minimum -> VGPR budget up to 256; we want ~48 so the
// scheduler has no occupancy incentive to serialize the 8 loads.
__global__ __launch_bounds__(256, 2) void lif_mem_update_kernel(
    const float* __restrict__ x, float* __restrict__ out, long long n4)
{
    const fx4* __restrict__ x4 = (const fx4*)x;
    fx4* __restrict__ o4 = (fx4*)out;

    long long base = ((long long)blockIdx.x * blockDim.x + threadIdx.x) * 2;
    if (base + 1 >= n4) return;   // n4 is even for this problem (2097152)

    // 8 independent loads: 2 consecutive fx4 from each of the 4 time planes.
    fx4 a0 = x4[base];            fx4 a1 = x4[base + 1];
    fx4 b0 = x4[base + n4];       fx4 b1 = x4[base + n4 + 1];
    fx4 c0 = x4[base + 2 * n4];   fx4 c1 = x4[base + 2 * n4 + 1];
    fx4 d0 = x4[base + 3 * n4];   fx4 d1 = x4[base + 3 * n4 + 1];

    // Hard fence: scheduler may not sink the loads below this point.
    __builtin_amdgcn_sched_barrier(0);

    fx4 zero = (fx4)(0.f);
    fx4 s0, s1, s2, s3, t0, t1, t2, t3;
    fx4 m, n;
    m = step4(zero, zero, a0, &s0);
    n = step4(zero, zero, a1, &t0);
    __builtin_nontemporal_store(s0, &o4[base]);
    __builtin_nontemporal_store(t0, &o4[base + 1]);
    m = step4(m, s0, b0, &s1);
    n = step4(n, t0, b1, &t1);
    __builtin_nontemporal_store(s1, &o4[base + n4]);
    __builtin_nontemporal_store(t1, &o4[base + n4 + 1]);
    m = step4(m, s1, c0, &s2);
    n = step4(n, t1, c1, &t2);
    __builtin_nontemporal_store(s2, &o4[base + 2 * n4]);
    __builtin_nontemporal_store(t2, &o4[base + 2 * n4 + 1]);
    m = step4(m, s2, d0, &s3);
    n = step4(n, t2, d1, &t3);
    __builtin_nontemporal_store(s3, &o4[base + 3 * n4]);
    __builtin_nontemporal_store(t3, &o4[base + 3 * n4 + 1]);
}

extern "C" void kernel_launch(void* const* d_in, const int* in_sizes, int n_in,
                              void* d_out, int out_size, void* d_ws, size_t ws_size,
                              hipStream_t stream)
{
    const float* x = (const float*)d_in[0];
    float* out = (float*)d_out;

    long long total = (long long)in_sizes[0];   // 33554432 floats = [4][8388608]
    long long nplane = total / 4;               // 8388608 floats per plane
    long long n4 = nplane / 4;                  // 2097152 float4 per plane

    const int block = 256;
    long long threads = n4 / 2;                 // 2 fx4 per thread
    long long grid = (threads + block - 1) / block;  // 4096 blocks
    lif_mem_update_kernel<<<(int)grid, block, 0, stream>>>(x, out, n4);
}

// Round 9
// 235.040 us; speedup vs baseline: 1.0190x; 1.0190x over previous
//
#include <hip/hip_runtime.h>

#define DECAY 0.25f

typedef float fx4 __attribute__((ext_vector_type(4)));

__device__ __forceinline__ fx4 step4(fx4 mem, fx4 spk, fx4 xi, fx4* s_out)
{
    fx4 m = (mem - spk * 0.5f) * DECAY + xi;
    fx4 s;
    s.x = rintf(fminf(fmaxf(m.x, 0.f), 1.f));
    s.y = rintf(fminf(fmaxf(m.y, 0.f), 1.f));
    s.z = rintf(fminf(fmaxf(m.z, 0.f), 1.f));
    s.w = rintf(fminf(fmaxf(m.w, 0.f), 1.f));
    *s_out = s;
    return m;
}

__global__ __launch_bounds__(256) void lif_mem_update_kernel(
    const float* __restrict__ x, float* __restrict__ out, long long n4)
{
    long long i = (long long)blockIdx.x * blockDim.x + threadIdx.x;
    if (i >= n4) return;

    const fx4* p0 = (const fx4*)x + i;
    const fx4* p1 = p0 + n4;
    const fx4* p2 = p1 + n4;
    const fx4* p3 = p2 + n4;
    fx4* o = (fx4*)out + i;

    // Forced 4-deep MLP: the compiler cannot sink or split inline asm.
    fx4 x0, x1, x2, x3;
    asm volatile(
        "global_load_dwordx4 %0, %4, off\n\t"
        "global_load_dwordx4 %1, %5, off\n\t"
        "global_load_dwordx4 %2, %6, off\n\t"
        "global_load_dwordx4 %3, %7, off"
        : "=&v"(x0), "=&v"(x1), "=&v"(x2), "=&v"(x3)
        : "v"(p0), "v"(p1), "v"(p2), "v"(p3));
    asm volatile("s_waitcnt vmcnt(0)" ::: "memory");
    __builtin_amdgcn_sched_barrier(0);   // rule #18: pin uses below the waitcnt

    fx4 zero = (fx4)(0.f);
    fx4 s0, s1, s2, s3;
    fx4 m;
    m = step4(zero, zero, x0, &s0);
    m = step4(m,    s0,   x1, &s1);
    m = step4(m,    s1,   x2, &s2);
    m = step4(m,    s2,   x3, &s3);

    o[0]      = s0;
    o[n4]     = s1;
    o[2 * n4] = s2;
    o[3 * n4] = s3;
}

extern "C" void kernel_launch(void* const* d_in, const int* in_sizes, int n_in,
                              void* d_out, int out_size, void* d_ws, size_t ws_size,
                              hipStream_t stream)
{
    const float* x = (const float*)d_in[0];
    float* out = (float*)d_out;

    long long total = (long long)in_sizes[0];   // 33554432 floats = [4][8388608]
    long long nplane = total / 4;               // 8388608 floats per plane
    long long n4 = nplane / 4;                  // 2097152 float4 per plane

    const int block = 256;
    long long grid = (n4 + block - 1) / block;  // 8192 blocks, one float4 per thread
    lif_mem_update_kernel<<<(int)grid, block, 0, stream>>>(x, out, n4);
}